// Round 14
// baseline (97.081 us; speedup 1.0000x reference)
//
#include <hip/hip_runtime.h>
#include <hip/hip_bf16.h>
#include <math.h>

#define VOCAB 30522
#define EMBED 768
#define NUM_CAT 18
#define HIS 50
#define SEQ 32
#define BATCH 64
#define CLICK_DIM 100

typedef short v8s __attribute__((ext_vector_type(8)));
typedef float v4f __attribute__((ext_vector_type(4)));
typedef unsigned short v8u __attribute__((ext_vector_type(8)));
typedef unsigned char v8c __attribute__((ext_vector_type(8)));

// ---------------- ws layout (byte offsets, 16B aligned) ----------------
#define OFF_POOLED 0            // bf16 [3200][768]           4,915,200 B
#define OFF_WT     4915200      // bf16 [768][768]            1,179,648 B
#define OFF_NR     6094848      // bf16 [3200][768]           4,915,200 B
#define OFF_NEWSW  15925248     // f32  [3200]                   12,800 B
#define OFF_FLAG   16177664     // int
#define OFF_QTAB   16252928     // int8 [30522][768]         23,440,896 B
#define OFF_DSCALE 39693824     // f32  [30522]                 122,088 B
#define OFF_LOGACC 39815936     // f32  [64*18]                   4,608 B
#define OFF_CLICKS 39820544     // f32  [64*18]                   4,608 B
#define OFF_CNTS   39825152     // int  [64*18]                   4,608 B
#define WS_NEED    39829760ull

// flag: 0 = int32 mask, 1 = uint8 (np.bool_) mask, 2 = float32 mask
__device__ __forceinline__ bool read_mask(const void* p, int i, int flag) {
    if (flag == 0) return ((const int*)p)[i] != 0;
    if (flag == 1) return ((const unsigned char*)p)[i] != 0;
    return ((const float*)p)[i] != 0.0f;
}

__device__ __forceinline__ float bf2f(unsigned short u) {
    union { unsigned int i; float f; } cv;
    cv.i = ((unsigned int)u) << 16;
    return cv.f;
}
__device__ __forceinline__ unsigned short f2bf(float f) {
    __hip_bfloat16 h = __float2bfloat16(f);
    return *(unsigned short*)&h;
}

// ---------------- KPREP: Wt transpose + detect + zero(news_w, logacc) + wemb->int8 ----------------
__global__ __launch_bounds__(256) void kprep(
        const float* __restrict__ W, __hip_bfloat16* __restrict__ Wt,
        const unsigned int* __restrict__ cm, int* __restrict__ flag_out,
        const float* __restrict__ wemb, signed char* __restrict__ qtab,
        float* __restrict__ dscales, float* __restrict__ news_w,
        float* __restrict__ logacc) {
    int blk = blockIdx.x;
    if (blk < 576) {
        __shared__ float t[32][33];
        int tx = threadIdx.x & 31, ty = threadIdx.x >> 5;
        int k0 = (blk % 24) * 32, n0 = (blk / 24) * 32;
        #pragma unroll
        for (int i = 0; i < 4; ++i)
            t[ty + i * 8][tx] = W[(size_t)(k0 + ty + i * 8) * EMBED + n0 + tx];
        __syncthreads();
        #pragma unroll
        for (int i = 0; i < 4; ++i)
            Wt[(size_t)(n0 + ty + i * 8) * EMBED + k0 + tx] =
                __float2bfloat16(t[tx][ty + i * 8]);
    } else if (blk == 576) {
        __shared__ int word_gt1, byte_gt1;
        if (threadIdx.x == 0) { word_gt1 = 0; byte_gt1 = 0; }
        __syncthreads();
        int lw = 0, lb = 0;
        for (int i = threadIdx.x; i < 14400; i += 256) {
            unsigned int v = cm[i];
            if (v > 1u) lw = 1;
            if ((v & 0xFFu) > 1u || ((v >> 8) & 0xFFu) > 1u ||
                ((v >> 16) & 0xFFu) > 1u || ((v >> 24) & 0xFFu) > 1u) lb = 1;
        }
        if (lw) atomicOr(&word_gt1, 1);
        if (lb) atomicOr(&byte_gt1, 1);
        for (int i = threadIdx.x; i < BATCH * HIS; i += 256) news_w[i] = 0.f;
        for (int i = threadIdx.x; i < BATCH * NUM_CAT; i += 256) logacc[i] = 0.f;
        __syncthreads();
        if (threadIdx.x == 0) {
            int f = 0;
            if (word_gt1) f = byte_gt1 ? 2 : 1;
            *flag_out = f;
        }
    } else {
        // per-row symmetric int8 quant: threads 0..191 own 4 consecutive cols
        __shared__ float red[4];
        int row = blk - 577;              // [0, 30522)
        int tid = threadIdx.x, lane = tid & 63, wv = tid >> 6;
        float4 v = make_float4(0.f, 0.f, 0.f, 0.f);
        if (tid < 192)
            v = *(const float4*)(wemb + (size_t)row * EMBED + tid * 4);
        float mx = fmaxf(fmaxf(fabsf(v.x), fabsf(v.y)),
                         fmaxf(fabsf(v.z), fabsf(v.w)));
        #pragma unroll
        for (int off = 32; off; off >>= 1) mx = fmaxf(mx, __shfl_xor(mx, off));
        if (lane == 0) red[wv] = mx;
        __syncthreads();
        float rowmax = fmaxf(fmaxf(red[0], red[1]), red[2]);
        if (tid < 192) {
            float inv = (rowmax > 0.f) ? 127.0f / rowmax : 0.f;
            int q0 = __float2int_rn(v.x * inv);
            int q1 = __float2int_rn(v.y * inv);
            int q2 = __float2int_rn(v.z * inv);
            int q3 = __float2int_rn(v.w * inv);
            q0 = max(-127, min(127, q0)); q1 = max(-127, min(127, q1));
            q2 = max(-127, min(127, q2)); q3 = max(-127, min(127, q3));
            char4 c; c.x = (signed char)q0; c.y = (signed char)q1;
            c.z = (signed char)q2; c.w = (signed char)q3;
            *(char4*)(qtab + (size_t)row * EMBED + tid * 4) = c;
        }
        if (tid == 0) dscales[row] = rowmax * (1.0f / 127.0f);
    }
}

// ---------------- K1C: gather (int8 table) + masked mean pool ----------------
__global__ __launch_bounds__(192) void k1c_pool(
        const int* __restrict__ enc, const void* amask,
        const unsigned char* __restrict__ qtab, const float* __restrict__ dscales,
        __hip_bfloat16* __restrict__ pooled, const int* __restrict__ flagp) {
    int tid = threadIdx.x, lane = tid & 63;
    int blk = blockIdx.x;                // [0,1600)
    int flag = *flagp;
    int bh0 = blk * 2, bh1 = blk * 2 + 1;
    bool mm = (lane < 32) ? read_mask(amask, bh0 * SEQ + lane, flag)
                          : read_mask(amask, bh1 * SEQ + (lane - 32), flag);
    unsigned long long bal = __ballot(mm);
    unsigned int mb0 = (unsigned int)(bal & 0xFFFFFFFFull);
    unsigned int mb1 = (unsigned int)(bal >> 32);
    int half = (tid >= 96) ? 1 : 0;
    int bh = half ? bh1 : bh0;
    unsigned int mb = half ? mb1 : mb0;
    float cnt = (float)__popc(mb);
    int slot = tid - half * 96;          // [0,96)
    const int* e = enc + bh * SEQ;
    float a[8] = {};
    v8c v[8], w[8];
    float ds[8], dw[8];
    #pragma unroll
    for (int j = 0; j < 8; ++j) {
        int tok = e[j];
        v[j] = ((const v8c*)(qtab + (size_t)tok * EMBED))[slot];
        ds[j] = dscales[tok];
    }
    #pragma unroll
    for (int s0 = 0; s0 < SEQ; s0 += 8) {
        if (s0 + 8 < SEQ) {
            #pragma unroll
            for (int j = 0; j < 8; ++j) {
                int tok = e[s0 + 8 + j];
                w[j] = ((const v8c*)(qtab + (size_t)tok * EMBED))[slot];
                dw[j] = dscales[tok];
            }
        }
        #pragma unroll
        for (int j = 0; j < 8; ++j) {
            float msc = ((mb >> (s0 + j)) & 1u) ? ds[j] : 0.f;
            #pragma unroll
            for (int k = 0; k < 8; ++k) {
                int q = (int)(signed char)v[j][k];
                a[k] = fmaf((float)q, msc, a[k]);
            }
        }
        #pragma unroll
        for (int j = 0; j < 8; ++j) { v[j] = w[j]; ds[j] = dw[j]; }
    }
    float d = 1.0f / fmaxf(cnt, 1.0f);
    v8u o;
    #pragma unroll
    for (int k = 0; k < 8; ++k) o[k] = f2bf(a[k] * d);
    *(v8u*)(((unsigned short*)pooled) + (size_t)bh * EMBED + slot * 8) = o;
}

// ---------------- fallback path (ws too small) ----------------
__global__ __launch_bounds__(1024) void k0_detect(
        const unsigned int* __restrict__ cm, int* flag_out, float* __restrict__ news_w) {
    __shared__ int word_gt1, byte_gt1;
    if (threadIdx.x == 0) { word_gt1 = 0; byte_gt1 = 0; }
    __syncthreads();
    int lw = 0, lb = 0;
    for (int i = threadIdx.x; i < 14400; i += blockDim.x) {
        unsigned int v = cm[i];
        if (v > 1u) lw = 1;
        if ((v & 0xFFu) > 1u || ((v >> 8) & 0xFFu) > 1u ||
            ((v >> 16) & 0xFFu) > 1u || ((v >> 24) & 0xFFu) > 1u) lb = 1;
    }
    if (lw) atomicOr(&word_gt1, 1);
    if (lb) atomicOr(&byte_gt1, 1);
    for (int i = threadIdx.x; i < BATCH * HIS; i += blockDim.x) news_w[i] = 0.f;
    __syncthreads();
    if (threadIdx.x == 0) {
        int f = 0;
        if (word_gt1) f = byte_gt1 ? 2 : 1;
        *flag_out = f;
    }
}

__global__ __launch_bounds__(256) void k2a_wt(
        const float* __restrict__ W, __hip_bfloat16* __restrict__ Wt) {
    __shared__ float t[32][33];
    int tx = threadIdx.x & 31, ty = threadIdx.x >> 5;
    int k0 = blockIdx.x * 32, n0 = blockIdx.y * 32;
    #pragma unroll
    for (int i = 0; i < 4; ++i)
        t[ty + i * 8][tx] = W[(size_t)(k0 + ty + i * 8) * EMBED + n0 + tx];
    __syncthreads();
    #pragma unroll
    for (int i = 0; i < 4; ++i)
        Wt[(size_t)(n0 + ty + i * 8) * EMBED + k0 + tx] =
            __float2bfloat16(t[tx][ty + i * 8]);
}

__global__ __launch_bounds__(192) void k1_pool(
        const int* __restrict__ enc, const void* amask,
        const float* __restrict__ wemb, __hip_bfloat16* __restrict__ pooled,
        const int* __restrict__ flagp) {
    int wave = threadIdx.x >> 6, lane = threadIdx.x & 63;
    int bh = blockIdx.x;
    int flag = *flagp;
    const int* e = enc + bh * SEQ;
    bool m = (lane < SEQ) ? read_mask(amask, bh * SEQ + lane, flag) : false;
    unsigned long long mb = __ballot(m);
    float cnt = (float)__popcll(mb);
    int fslot = wave * 64 + lane;
    float ax = 0.f, ay = 0.f, az = 0.f, aw = 0.f;
    #pragma unroll
    for (int s0 = 0; s0 < SEQ; s0 += 8) {
        float4 v[8];
        #pragma unroll
        for (int j = 0; j < 8; ++j)
            v[j] = ((const float4*)(wemb + (size_t)e[s0 + j] * EMBED))[fslot];
        #pragma unroll
        for (int j = 0; j < 8; ++j) {
            float mmv = ((mb >> (s0 + j)) & 1ull) ? 1.0f : 0.0f;
            ax += mmv * v[j].x; ay += mmv * v[j].y;
            az += mmv * v[j].z; aw += mmv * v[j].w;
        }
    }
    float d = 1.0f / fmaxf(cnt, 1.0f);
    ushort4 pk;
    pk.x = f2bf(ax * d); pk.y = f2bf(ay * d);
    pk.z = f2bf(az * d); pk.w = f2bf(aw * d);
    *(ushort4*)((unsigned short*)pooled + (size_t)bh * EMBED + fslot * 4) = pk;
}

// ---------------- K2: news_repr = tanh(pooled @ W + b) -> bf16, + fused news_w ----------------
#define BM 64
#define BN 64
#define GBK 64
#define LDP 72
__global__ __launch_bounds__(256) void k2_mfma(
        const __hip_bfloat16* __restrict__ A,
        const __hip_bfloat16* __restrict__ Bt,
        const float* __restrict__ bias,
        const float* __restrict__ wna,
        unsigned short* __restrict__ C,
        float* __restrict__ news_w) {
    __shared__ short As[BM * LDP];
    __shared__ short Bs[BN * LDP];
    int tid = threadIdx.x;
    int wave = tid >> 6, lane = tid & 63;
    int l15 = lane & 15, l4 = lane >> 4;
    int wr = wave >> 1, wc = wave & 1;
    int row0 = blockIdx.x * BM;
    int col0 = blockIdx.y * BN;
    v4f acc[2][2] = {};

    int ra[2], ca[2];
    #pragma unroll
    for (int it = 0; it < 2; ++it) {
        int chunk = tid + it * 256;
        ra[it] = chunk >> 3; ca[it] = chunk & 7;
    }

    v8s pa[2], pb[2];
    #pragma unroll
    for (int it = 0; it < 2; ++it) {
        pa[it] = *(const v8s*)(A  + (size_t)(row0 + ra[it]) * EMBED + ca[it] * 8);
        pb[it] = *(const v8s*)(Bt + (size_t)(col0 + ra[it]) * EMBED + ca[it] * 8);
    }

    for (int s = 0; s < EMBED / GBK; ++s) {
        #pragma unroll
        for (int it = 0; it < 2; ++it) {
            *(v8s*)&As[ra[it] * LDP + ca[it] * 8] = pa[it];
            *(v8s*)&Bs[ra[it] * LDP + ca[it] * 8] = pb[it];
        }
        __syncthreads();
        if (s < EMBED / GBK - 1) {
            int k0 = (s + 1) * GBK;
            #pragma unroll
            for (int it = 0; it < 2; ++it) {
                pa[it] = *(const v8s*)(A  + (size_t)(row0 + ra[it]) * EMBED + k0 + ca[it] * 8);
                pb[it] = *(const v8s*)(Bt + (size_t)(col0 + ra[it]) * EMBED + k0 + ca[it] * 8);
            }
        }
        #pragma unroll
        for (int kk = 0; kk < 2; ++kk) {
            v8s af[2], bf_[2];
            #pragma unroll
            for (int mi = 0; mi < 2; ++mi)
                af[mi] = *(const v8s*)&As[(wr * 32 + mi * 16 + l15) * LDP + kk * 32 + l4 * 8];
            #pragma unroll
            for (int ni = 0; ni < 2; ++ni)
                bf_[ni] = *(const v8s*)&Bs[(wc * 32 + ni * 16 + l15) * LDP + kk * 32 + l4 * 8];
            #pragma unroll
            for (int mi = 0; mi < 2; ++mi)
                #pragma unroll
                for (int ni = 0; ni < 2; ++ni)
                    acc[mi][ni] = __builtin_amdgcn_mfma_f32_16x16x32_bf16(
                        af[mi], bf_[ni], acc[mi][ni], 0, 0, 0);
        }
        __syncthreads();
    }
    float bcol[2], wcol[2];
    #pragma unroll
    for (int ni = 0; ni < 2; ++ni) {
        int col = col0 + wc * 32 + ni * 16 + l15;
        bcol[ni] = bias[col]; wcol[ni] = wna[col];
    }
    #pragma unroll
    for (int mi = 0; mi < 2; ++mi) {
        #pragma unroll
        for (int r = 0; r < 4; ++r) {
            int row = row0 + wr * 32 + mi * 16 + l4 * 4 + r;
            float pr = 0.f;
            #pragma unroll
            for (int ni = 0; ni < 2; ++ni) {
                int col = col0 + wc * 32 + ni * 16 + l15;
                float tv = tanhf(acc[mi][ni][r] + bcol[ni]);
                C[(size_t)row * EMBED + col] = f2bf(tv);
                pr += tv * wcol[ni];
            }
            pr += __shfl_xor(pr, 1); pr += __shfl_xor(pr, 2);
            pr += __shfl_xor(pr, 4); pr += __shfl_xor(pr, 8);
            if (l15 == 0) atomicAdd(&news_w[row], pr);
        }
    }
}

// ---------------- K4A: (b, col-third) -> cat softmax + einsum slice + partial logits ----------------
// grid 192 = 64 b x 3 thirds; 256 threads, thread owns one col
__global__ __launch_bounds__(256) void k4a_cat(
        const void* cmask, const unsigned short* __restrict__ nr,
        const float* __restrict__ news_w, const float* __restrict__ cat_emb,
        const float* __restrict__ w_cat, const float* __restrict__ click_emb,
        const float* __restrict__ click_w, const float* __restrict__ click_b,
        float* __restrict__ out_cat, float* __restrict__ logacc,
        float* __restrict__ clicks_ws, int* __restrict__ cnts_ws,
        const int* __restrict__ flagp) {
    int blk = blockIdx.x;
    int b = blk / 3, third = blk % 3;
    int tid = threadIdx.x, wave = tid >> 6, lane = tid & 63;
    int flag = *flagp;
    __shared__ float plds[HIS][20];
    __shared__ float redbuf[NUM_CAT][4];

    // phase 1: per-cat masked softmax (all thirds recompute; third 0 owns click/cnt)
    for (int c = wave; c < NUM_CAT; c += 4) {
        bool m = false; float v = -INFINITY;
        if (lane < HIS) {
            m = read_mask(cmask, (b * NUM_CAT + c) * HIS + lane, flag);
            if (m) v = news_w[b * HIS + lane];
        }
        unsigned long long bal = __ballot(m);
        int cnt = __popcll(bal);
        float maxv = v;
        #pragma unroll
        for (int off = 32; off; off >>= 1) maxv = fmaxf(maxv, __shfl_xor(maxv, off));
        float e = (v == -INFINITY) ? 0.f : expf(v - maxv);
        float sum = e;
        #pragma unroll
        for (int off = 32; off; off >>= 1) sum += __shfl_xor(sum, off);
        if (lane < HIS)
            plds[lane][c] = (cnt == 0 || v == -INFINITY) ? 0.f : e / sum;
        if (third == 0) {
            float cs = 0.f;
            if (lane < HIS) {
                const float* ce = click_emb + (size_t)cnt * CLICK_DIM;
                cs = ce[lane] * click_w[lane] + ce[lane + HIS] * click_w[lane + HIS];
            }
            #pragma unroll
            for (int off = 32; off; off >>= 1) cs += __shfl_down(cs, off);
            if (lane == 0) {
                cnts_ws[b * NUM_CAT + c] = cnt;
                clicks_ws[b * NUM_CAT + c] = cs + click_b[0];
            }
        }
    }
    __syncthreads();

    // phase 2: einsum for this third's 256 cols
    int col = third * 256 + tid;
    const unsigned short* nrb = nr + (size_t)b * HIS * EMBED;
    float acc[NUM_CAT];
    #pragma unroll
    for (int c = 0; c < NUM_CAT; ++c) acc[c] = 0.f;
    #pragma unroll 5
    for (int h = 0; h < HIS; ++h) {
        float v = bf2f(nrb[h * EMBED + col]);
        #pragma unroll
        for (int c = 0; c < NUM_CAT; ++c) acc[c] += plds[h][c] * v;
    }
    float wv = w_cat[col];
    float* ocb = out_cat + (size_t)b * NUM_CAT * EMBED;
    #pragma unroll
    for (int c = 0; c < NUM_CAT; ++c) {
        float o = acc[c] + cat_emb[c * EMBED + col];
        ocb[c * EMBED + col] = o;
        float s = o * wv;
        #pragma unroll
        for (int off = 32; off; off >>= 1) s += __shfl_down(s, off);
        if (lane == 0) redbuf[c][wave] = s;
    }
    __syncthreads();
    if (tid < NUM_CAT) {
        float s = redbuf[tid][0] + redbuf[tid][1] + redbuf[tid][2] + redbuf[tid][3];
        atomicAdd(&logacc[b * NUM_CAT + tid], s);
    }
}

// ---------------- K4B: final logits + softmax over C + user ----------------
__global__ __launch_bounds__(768) void k4b_user(
        const float* __restrict__ logacc, const float* __restrict__ clicks_ws,
        const int* __restrict__ cnts_ws, const float* __restrict__ out_cat,
        float* __restrict__ user) {
    int b = blockIdx.x, tid = threadIdx.x;
    __shared__ float logit[NUM_CAT];
    if (tid < NUM_CAT) {
        int cnt = cnts_ws[b * NUM_CAT + tid];
        logit[tid] = (cnt == 0) ? -INFINITY
                     : (logacc[b * NUM_CAT + tid] + clicks_ws[b * NUM_CAT + tid]);
    }
    __syncthreads();
    float maxv = -INFINITY;
    #pragma unroll
    for (int c = 0; c < NUM_CAT; ++c) maxv = fmaxf(maxv, logit[c]);
    float sum = 0.f;
    #pragma unroll
    for (int c = 0; c < NUM_CAT; ++c)
        sum += (logit[c] == -INFINITY) ? 0.f : expf(logit[c] - maxv);
    const float* ocb = out_cat + (size_t)b * NUM_CAT * EMBED;
    float u = 0.f;
    #pragma unroll
    for (int c = 0; c < NUM_CAT; ++c) {
        float w = (logit[c] == -INFINITY) ? 0.f : expf(logit[c] - maxv) / sum;
        u += w * ocb[c * EMBED + tid];
    }
    user[(size_t)b * EMBED + tid] = u;
}

// ---------------- K4 (fallback single-kernel tail, small-ws path) ----------------
__global__ __launch_bounds__(768) void k4_fused(
        const void* cmask, const unsigned short* __restrict__ nr,
        const float* __restrict__ news_w, const float* __restrict__ cat_emb,
        const float* __restrict__ w_cat, const float* __restrict__ click_emb,
        const float* __restrict__ click_w, const float* __restrict__ click_b,
        float* __restrict__ out_cat, float* __restrict__ user,
        const int* __restrict__ flagp) {
    int b = blockIdx.x, tid = threadIdx.x;
    int wave = tid >> 6, lane = tid & 63;
    int flag = *flagp;
    __shared__ float plds[HIS][20];
    __shared__ float redbuf[NUM_CAT][12];
    __shared__ float clicks[NUM_CAT];
    __shared__ int   cnts[NUM_CAT];
    __shared__ float logit[NUM_CAT];

    for (int c = wave; c < NUM_CAT; c += 12) {
        bool m = false; float v = -INFINITY;
        if (lane < HIS) {
            m = read_mask(cmask, (b * NUM_CAT + c) * HIS + lane, flag);
            if (m) v = news_w[b * HIS + lane];
        }
        unsigned long long bal = __ballot(m);
        int cnt = __popcll(bal);
        float maxv = v;
        #pragma unroll
        for (int off = 32; off; off >>= 1) maxv = fmaxf(maxv, __shfl_xor(maxv, off));
        float e = (v == -INFINITY) ? 0.f : expf(v - maxv);
        float sum = e;
        #pragma unroll
        for (int off = 32; off; off >>= 1) sum += __shfl_xor(sum, off);
        if (lane < HIS)
            plds[lane][c] = (cnt == 0 || v == -INFINITY) ? 0.f : e / sum;
        float cs = 0.f;
        if (lane < HIS) {
            const float* ce = click_emb + (size_t)cnt * CLICK_DIM;
            cs = ce[lane] * click_w[lane] + ce[lane + HIS] * click_w[lane + HIS];
        }
        #pragma unroll
        for (int off = 32; off; off >>= 1) cs += __shfl_down(cs, off);
        if (lane == 0) { cnts[c] = cnt; clicks[c] = cs + click_b[0]; }
    }
    __syncthreads();

    int col = tid;
    const unsigned short* nrb = nr + (size_t)b * HIS * EMBED;
    float acc[NUM_CAT];
    #pragma unroll
    for (int c = 0; c < NUM_CAT; ++c) acc[c] = 0.f;
    #pragma unroll 5
    for (int h = 0; h < HIS; ++h) {
        float v = bf2f(nrb[h * EMBED + col]);
        #pragma unroll
        for (int c = 0; c < NUM_CAT; ++c) acc[c] += plds[h][c] * v;
    }
    float part[NUM_CAT];
    float wv = w_cat[col];
    float* ocb = out_cat + (size_t)b * NUM_CAT * EMBED;
    #pragma unroll
    for (int c = 0; c < NUM_CAT; ++c) {
        float o = acc[c] + cat_emb[c * EMBED + col];
        acc[c] = o;
        ocb[c * EMBED + col] = o;
        part[c] = o * wv;
    }
    #pragma unroll
    for (int c = 0; c < NUM_CAT; ++c) {
        float s = part[c];
        #pragma unroll
        for (int off = 32; off; off >>= 1) s += __shfl_down(s, off);
        if (lane == 0) redbuf[c][wave] = s;
    }
    __syncthreads();
    if (tid < NUM_CAT) {
        float s = 0.f;
        #pragma unroll
        for (int w = 0; w < 12; ++w) s += redbuf[tid][w];
        logit[tid] = (cnts[tid] == 0) ? -INFINITY : (s + clicks[tid]);
    }
    __syncthreads();

    float maxv = -INFINITY;
    #pragma unroll
    for (int c = 0; c < NUM_CAT; ++c) maxv = fmaxf(maxv, logit[c]);
    float sum = 0.f;
    #pragma unroll
    for (int c = 0; c < NUM_CAT; ++c)
        sum += (logit[c] == -INFINITY) ? 0.f : expf(logit[c] - maxv);
    float u = 0.f;
    #pragma unroll
    for (int c = 0; c < NUM_CAT; ++c) {
        float w = (logit[c] == -INFINITY) ? 0.f : expf(logit[c] - maxv) / sum;
        u += w * acc[c];
    }
    user[(size_t)b * EMBED + col] = u;
}

extern "C" void kernel_launch(void* const* d_in, const int* in_sizes, int n_in,
                              void* d_out, int out_size, void* d_ws, size_t ws_size,
                              hipStream_t stream) {
    const int*   enc    = (const int*)d_in[0];
    const void*  amask  = d_in[1];
    const void*  cmask  = d_in[2];
    const float* wemb   = (const float*)d_in[3];
    const float* projw  = (const float*)d_in[4];
    const float* projb  = (const float*)d_in[5];
    const float* catemb = (const float*)d_in[6];
    const float* wna    = (const float*)d_in[7];
    const float* wca    = (const float*)d_in[8];
    const float* clemb  = (const float*)d_in[9];
    const float* clw    = (const float*)d_in[10];
    const float* clb    = (const float*)d_in[11];

    unsigned char* wsb = (unsigned char*)d_ws;
    __hip_bfloat16* pooled = (__hip_bfloat16*)(wsb + OFF_POOLED);
    __hip_bfloat16* Wt     = (__hip_bfloat16*)(wsb + OFF_WT);
    unsigned short* nr     = (unsigned short*)(wsb + OFF_NR);
    float* news_w = (float*)(wsb + OFF_NEWSW);
    int*   flag   = (int*)(wsb + OFF_FLAG);
    signed char* qtab = (signed char*)(wsb + OFF_QTAB);
    float* dscales = (float*)(wsb + OFF_DSCALE);
    float* logacc  = (float*)(wsb + OFF_LOGACC);
    float* clicks  = (float*)(wsb + OFF_CLICKS);
    int*   cnts    = (int*)(wsb + OFF_CNTS);

    float* out_cat = (float*)d_out;
    float* user    = (float*)d_out + BATCH * NUM_CAT * EMBED;

    if (ws_size >= WS_NEED) {
        kprep<<<577 + VOCAB, 256, 0, stream>>>(
            projw, Wt, (const unsigned int*)cmask, flag, wemb, qtab, dscales,
            news_w, logacc);
        k1c_pool<<<1600, 192, 0, stream>>>(enc, amask, (const unsigned char*)qtab,
                                           dscales, pooled, flag);
        dim3 g2(50, 12);
        k2_mfma<<<g2, 256, 0, stream>>>(pooled, Wt, projb, wna, nr, news_w);
        k4a_cat<<<BATCH * 3, 256, 0, stream>>>(cmask, nr, news_w, catemb, wca,
                                               clemb, clw, clb, out_cat, logacc,
                                               clicks, cnts, flag);
        k4b_user<<<BATCH, 768, 0, stream>>>(logacc, clicks, cnts, out_cat, user);
    } else {
        k0_detect<<<1, 1024, 0, stream>>>((const unsigned int*)cmask, flag, news_w);
        dim3 gt(24, 24);
        k2a_wt<<<gt, 256, 0, stream>>>(projw, Wt);
        k1_pool<<<3200, 192, 0, stream>>>(enc, amask, wemb, pooled, flag);
        dim3 g2(50, 12);
        k2_mfma<<<g2, 256, 0, stream>>>(pooled, Wt, projb, wna, nr, news_w);
        k4_fused<<<BATCH, 768, 0, stream>>>(cmask, nr, news_w, catemb, wca,
                                            clemb, clw, clb, out_cat, user, flag);
    }
}

// Round 15
// 76.564 us; speedup vs baseline: 1.2680x; 1.2680x over previous
//
#include <hip/hip_runtime.h>
#include <hip/hip_bf16.h>
#include <math.h>

#define VOCAB 30522
#define EMBED 768
#define NUM_CAT 18
#define HIS 50
#define SEQ 32
#define BATCH 64
#define CLICK_DIM 100

typedef short v8s __attribute__((ext_vector_type(8)));
typedef float v4f __attribute__((ext_vector_type(4)));
typedef unsigned short v8u __attribute__((ext_vector_type(8)));
typedef unsigned char v8c __attribute__((ext_vector_type(8)));

// ---------------- ws layout (byte offsets, 16B aligned) ----------------
#define OFF_POOLED 0            // bf16 [3200][768]           4,915,200 B
#define OFF_WT     4915200      // bf16 [768][768]            1,179,648 B
#define OFF_NR     6094848      // bf16 [3200][768]           4,915,200 B
#define OFF_NEWSW  15925248     // f32  [3200]                   12,800 B
#define OFF_FLAG   16177664     // int
#define OFF_QTAB   16252928     // int8 [30522][768]         23,440,896 B
#define OFF_DSCALE 39693824     // f32  [30522]                 122,088 B
#define WS_NEED    39815912ull

// flag: 0 = int32 mask, 1 = uint8 (np.bool_) mask, 2 = float32 mask
__device__ __forceinline__ bool read_mask(const void* p, int i, int flag) {
    if (flag == 0) return ((const int*)p)[i] != 0;
    if (flag == 1) return ((const unsigned char*)p)[i] != 0;
    return ((const float*)p)[i] != 0.0f;
}

__device__ __forceinline__ float bf2f(unsigned short u) {
    union { unsigned int i; float f; } cv;
    cv.i = ((unsigned int)u) << 16;
    return cv.f;
}
__device__ __forceinline__ unsigned short f2bf(float f) {
    __hip_bfloat16 h = __float2bfloat16(f);
    return *(unsigned short*)&h;
}

// ---------------- KPREP: Wt transpose + mask detect + news_w zero + wemb->int8 ----------------
// blocks [0,576): Wt transpose; 576: detect+zero; [577, 577+30522): per-row int8 quant
__global__ __launch_bounds__(256) void kprep(
        const float* __restrict__ W, __hip_bfloat16* __restrict__ Wt,
        const unsigned int* __restrict__ cm, int* __restrict__ flag_out,
        const float* __restrict__ wemb, signed char* __restrict__ qtab,
        float* __restrict__ dscales, float* __restrict__ news_w) {
    int blk = blockIdx.x;
    if (blk < 576) {
        __shared__ float t[32][33];
        int tx = threadIdx.x & 31, ty = threadIdx.x >> 5;
        int k0 = (blk % 24) * 32, n0 = (blk / 24) * 32;
        #pragma unroll
        for (int i = 0; i < 4; ++i)
            t[ty + i * 8][tx] = W[(size_t)(k0 + ty + i * 8) * EMBED + n0 + tx];
        __syncthreads();
        #pragma unroll
        for (int i = 0; i < 4; ++i)
            Wt[(size_t)(n0 + ty + i * 8) * EMBED + k0 + tx] =
                __float2bfloat16(t[tx][ty + i * 8]);
    } else if (blk == 576) {
        __shared__ int word_gt1, byte_gt1;
        if (threadIdx.x == 0) { word_gt1 = 0; byte_gt1 = 0; }
        __syncthreads();
        int lw = 0, lb = 0;
        for (int i = threadIdx.x; i < 14400; i += 256) {
            unsigned int v = cm[i];
            if (v > 1u) lw = 1;
            if ((v & 0xFFu) > 1u || ((v >> 8) & 0xFFu) > 1u ||
                ((v >> 16) & 0xFFu) > 1u || ((v >> 24) & 0xFFu) > 1u) lb = 1;
        }
        if (lw) atomicOr(&word_gt1, 1);
        if (lb) atomicOr(&byte_gt1, 1);
        for (int i = threadIdx.x; i < BATCH * HIS; i += 256) news_w[i] = 0.f;
        __syncthreads();
        if (threadIdx.x == 0) {
            int f = 0;
            if (word_gt1) f = byte_gt1 ? 2 : 1;
            *flag_out = f;
        }
    } else {
        // per-row symmetric int8 quant: threads 0..191 own 4 consecutive cols
        __shared__ float red[4];
        int row = blk - 577;              // [0, 30522)
        int tid = threadIdx.x, lane = tid & 63, wv = tid >> 6;
        float4 v = make_float4(0.f, 0.f, 0.f, 0.f);
        if (tid < 192)
            v = *(const float4*)(wemb + (size_t)row * EMBED + tid * 4);
        float mx = fmaxf(fmaxf(fabsf(v.x), fabsf(v.y)),
                         fmaxf(fabsf(v.z), fabsf(v.w)));
        #pragma unroll
        for (int off = 32; off; off >>= 1) mx = fmaxf(mx, __shfl_xor(mx, off));
        if (lane == 0) red[wv] = mx;
        __syncthreads();
        float rowmax = fmaxf(fmaxf(red[0], red[1]), red[2]);
        if (tid < 192) {
            float inv = (rowmax > 0.f) ? 127.0f / rowmax : 0.f;
            int q0 = __float2int_rn(v.x * inv);
            int q1 = __float2int_rn(v.y * inv);
            int q2 = __float2int_rn(v.z * inv);
            int q3 = __float2int_rn(v.w * inv);
            q0 = max(-127, min(127, q0)); q1 = max(-127, min(127, q1));
            q2 = max(-127, min(127, q2)); q3 = max(-127, min(127, q3));
            char4 c; c.x = (signed char)q0; c.y = (signed char)q1;
            c.z = (signed char)q2; c.w = (signed char)q3;
            *(char4*)(qtab + (size_t)row * EMBED + tid * 4) = c;
        }
        if (tid == 0) dscales[row] = rowmax * (1.0f / 127.0f);
    }
}

// ---------------- K1C: gather (int8 table) + masked mean pool, 16-deep pipeline ----------------
// 2 rows per block, 192 threads; thread owns uchar8 (8B) slot: 96 slots/row
__global__ __launch_bounds__(192) void k1c_pool(
        const int* __restrict__ enc, const void* amask,
        const unsigned char* __restrict__ qtab, const float* __restrict__ dscales,
        __hip_bfloat16* __restrict__ pooled, const int* __restrict__ flagp) {
    int tid = threadIdx.x, lane = tid & 63;
    int blk = blockIdx.x;                // [0,1600)
    int flag = *flagp;
    int bh0 = blk * 2, bh1 = blk * 2 + 1;
    bool mm = (lane < 32) ? read_mask(amask, bh0 * SEQ + lane, flag)
                          : read_mask(amask, bh1 * SEQ + (lane - 32), flag);
    unsigned long long bal = __ballot(mm);
    unsigned int mb0 = (unsigned int)(bal & 0xFFFFFFFFull);
    unsigned int mb1 = (unsigned int)(bal >> 32);
    int half = (tid >= 96) ? 1 : 0;
    int bh = half ? bh1 : bh0;
    unsigned int mb = half ? mb1 : mb0;
    float cnt = (float)__popc(mb);
    int slot = tid - half * 96;          // [0,96)
    const int* e = enc + bh * SEQ;
    float a[8] = {};
    v8c v[8], w[8];
    float ds[8], dw[8];
    #pragma unroll
    for (int j = 0; j < 8; ++j) {
        int tok = e[j];
        v[j] = ((const v8c*)(qtab + (size_t)tok * EMBED))[slot];
        ds[j] = dscales[tok];
    }
    #pragma unroll
    for (int s0 = 0; s0 < SEQ; s0 += 8) {
        if (s0 + 8 < SEQ) {
            #pragma unroll
            for (int j = 0; j < 8; ++j) {
                int tok = e[s0 + 8 + j];
                w[j] = ((const v8c*)(qtab + (size_t)tok * EMBED))[slot];
                dw[j] = dscales[tok];
            }
        }
        #pragma unroll
        for (int j = 0; j < 8; ++j) {
            float msc = ((mb >> (s0 + j)) & 1u) ? ds[j] : 0.f;
            #pragma unroll
            for (int k = 0; k < 8; ++k) {
                int q = (int)(signed char)v[j][k];
                a[k] = fmaf((float)q, msc, a[k]);
            }
        }
        #pragma unroll
        for (int j = 0; j < 8; ++j) { v[j] = w[j]; ds[j] = dw[j]; }
    }
    float d = 1.0f / fmaxf(cnt, 1.0f);
    v8u o;
    #pragma unroll
    for (int k = 0; k < 8; ++k) o[k] = f2bf(a[k] * d);
    *(v8u*)(((unsigned short*)pooled) + (size_t)bh * EMBED + slot * 8) = o;
}

// ---------------- fallback path (ws too small) ----------------
__global__ __launch_bounds__(1024) void k0_detect(
        const unsigned int* __restrict__ cm, int* flag_out, float* __restrict__ news_w) {
    __shared__ int word_gt1, byte_gt1;
    if (threadIdx.x == 0) { word_gt1 = 0; byte_gt1 = 0; }
    __syncthreads();
    int lw = 0, lb = 0;
    for (int i = threadIdx.x; i < 14400; i += blockDim.x) {
        unsigned int v = cm[i];
        if (v > 1u) lw = 1;
        if ((v & 0xFFu) > 1u || ((v >> 8) & 0xFFu) > 1u ||
            ((v >> 16) & 0xFFu) > 1u || ((v >> 24) & 0xFFu) > 1u) lb = 1;
    }
    if (lw) atomicOr(&word_gt1, 1);
    if (lb) atomicOr(&byte_gt1, 1);
    for (int i = threadIdx.x; i < BATCH * HIS; i += blockDim.x) news_w[i] = 0.f;
    __syncthreads();
    if (threadIdx.x == 0) {
        int f = 0;
        if (word_gt1) f = byte_gt1 ? 2 : 1;
        *flag_out = f;
    }
}

__global__ __launch_bounds__(256) void k2a_wt(
        const float* __restrict__ W, __hip_bfloat16* __restrict__ Wt) {
    __shared__ float t[32][33];
    int tx = threadIdx.x & 31, ty = threadIdx.x >> 5;
    int k0 = blockIdx.x * 32, n0 = blockIdx.y * 32;
    #pragma unroll
    for (int i = 0; i < 4; ++i)
        t[ty + i * 8][tx] = W[(size_t)(k0 + ty + i * 8) * EMBED + n0 + tx];
    __syncthreads();
    #pragma unroll
    for (int i = 0; i < 4; ++i)
        Wt[(size_t)(n0 + ty + i * 8) * EMBED + k0 + tx] =
            __float2bfloat16(t[tx][ty + i * 8]);
}

__global__ __launch_bounds__(192) void k1_pool(
        const int* __restrict__ enc, const void* amask,
        const float* __restrict__ wemb, __hip_bfloat16* __restrict__ pooled,
        const int* __restrict__ flagp) {
    int wave = threadIdx.x >> 6, lane = threadIdx.x & 63;
    int bh = blockIdx.x;
    int flag = *flagp;
    const int* e = enc + bh * SEQ;
    bool m = (lane < SEQ) ? read_mask(amask, bh * SEQ + lane, flag) : false;
    unsigned long long mb = __ballot(m);
    float cnt = (float)__popcll(mb);
    int fslot = wave * 64 + lane;
    float ax = 0.f, ay = 0.f, az = 0.f, aw = 0.f;
    #pragma unroll
    for (int s0 = 0; s0 < SEQ; s0 += 8) {
        float4 v[8];
        #pragma unroll
        for (int j = 0; j < 8; ++j)
            v[j] = ((const float4*)(wemb + (size_t)e[s0 + j] * EMBED))[fslot];
        #pragma unroll
        for (int j = 0; j < 8; ++j) {
            float mmv = ((mb >> (s0 + j)) & 1ull) ? 1.0f : 0.0f;
            ax += mmv * v[j].x; ay += mmv * v[j].y;
            az += mmv * v[j].z; aw += mmv * v[j].w;
        }
    }
    float d = 1.0f / fmaxf(cnt, 1.0f);
    ushort4 pk;
    pk.x = f2bf(ax * d); pk.y = f2bf(ay * d);
    pk.z = f2bf(az * d); pk.w = f2bf(aw * d);
    *(ushort4*)((unsigned short*)pooled + (size_t)bh * EMBED + fslot * 4) = pk;
}

// ---------------- K2: news_repr = tanh(pooled @ W + b) -> bf16, + fused news_w ----------------
// 64x64 tile, BK=64, 4 waves (2x2, each 32x32 = 2x2 frags), grid 50x12 = 600 blocks
#define BM 64
#define BN 64
#define GBK 64
#define LDP 72
__global__ __launch_bounds__(256) void k2_mfma(
        const __hip_bfloat16* __restrict__ A,   // pooled [3200][768]
        const __hip_bfloat16* __restrict__ Bt,  // Wt [768(n)][768(k)]
        const float* __restrict__ bias,
        const float* __restrict__ wna,          // w_news_attn [768]
        unsigned short* __restrict__ C,         // news_repr bf16 [3200][768]
        float* __restrict__ news_w) {           // [3200], pre-zeroed
    __shared__ short As[BM * LDP];
    __shared__ short Bs[BN * LDP];
    int tid = threadIdx.x;
    int wave = tid >> 6, lane = tid & 63;
    int l15 = lane & 15, l4 = lane >> 4;
    int wr = wave >> 1, wc = wave & 1;
    int row0 = blockIdx.x * BM;
    int col0 = blockIdx.y * BN;
    v4f acc[2][2] = {};

    int ra[2], ca[2];
    #pragma unroll
    for (int it = 0; it < 2; ++it) {
        int chunk = tid + it * 256;
        ra[it] = chunk >> 3; ca[it] = chunk & 7;
    }

    v8s pa[2], pb[2];
    #pragma unroll
    for (int it = 0; it < 2; ++it) {
        pa[it] = *(const v8s*)(A  + (size_t)(row0 + ra[it]) * EMBED + ca[it] * 8);
        pb[it] = *(const v8s*)(Bt + (size_t)(col0 + ra[it]) * EMBED + ca[it] * 8);
    }

    for (int s = 0; s < EMBED / GBK; ++s) {
        #pragma unroll
        for (int it = 0; it < 2; ++it) {
            *(v8s*)&As[ra[it] * LDP + ca[it] * 8] = pa[it];
            *(v8s*)&Bs[ra[it] * LDP + ca[it] * 8] = pb[it];
        }
        __syncthreads();
        if (s < EMBED / GBK - 1) {
            int k0 = (s + 1) * GBK;
            #pragma unroll
            for (int it = 0; it < 2; ++it) {
                pa[it] = *(const v8s*)(A  + (size_t)(row0 + ra[it]) * EMBED + k0 + ca[it] * 8);
                pb[it] = *(const v8s*)(Bt + (size_t)(col0 + ra[it]) * EMBED + k0 + ca[it] * 8);
            }
        }
        #pragma unroll
        for (int kk = 0; kk < 2; ++kk) {
            v8s af[2], bf_[2];
            #pragma unroll
            for (int mi = 0; mi < 2; ++mi)
                af[mi] = *(const v8s*)&As[(wr * 32 + mi * 16 + l15) * LDP + kk * 32 + l4 * 8];
            #pragma unroll
            for (int ni = 0; ni < 2; ++ni)
                bf_[ni] = *(const v8s*)&Bs[(wc * 32 + ni * 16 + l15) * LDP + kk * 32 + l4 * 8];
            #pragma unroll
            for (int mi = 0; mi < 2; ++mi)
                #pragma unroll
                for (int ni = 0; ni < 2; ++ni)
                    acc[mi][ni] = __builtin_amdgcn_mfma_f32_16x16x32_bf16(
                        af[mi], bf_[ni], acc[mi][ni], 0, 0, 0);
        }
        __syncthreads();
    }
    float bcol[2], wcol[2];
    #pragma unroll
    for (int ni = 0; ni < 2; ++ni) {
        int col = col0 + wc * 32 + ni * 16 + l15;
        bcol[ni] = bias[col]; wcol[ni] = wna[col];
    }
    #pragma unroll
    for (int mi = 0; mi < 2; ++mi) {
        #pragma unroll
        for (int r = 0; r < 4; ++r) {
            int row = row0 + wr * 32 + mi * 16 + l4 * 4 + r;
            float pr = 0.f;
            #pragma unroll
            for (int ni = 0; ni < 2; ++ni) {
                int col = col0 + wc * 32 + ni * 16 + l15;
                float tv = tanhf(acc[mi][ni][r] + bcol[ni]);
                C[(size_t)row * EMBED + col] = f2bf(tv);
                pr += tv * wcol[ni];
            }
            pr += __shfl_xor(pr, 1); pr += __shfl_xor(pr, 2);
            pr += __shfl_xor(pr, 4); pr += __shfl_xor(pr, 8);
            if (l15 == 0) atomicAdd(&news_w[row], pr);
        }
    }
}

// ---------------- K4: fused cat softmax + einsum + logits + user ----------------
__global__ __launch_bounds__(768) void k4_fused(
        const void* cmask, const unsigned short* __restrict__ nr,
        const float* __restrict__ news_w, const float* __restrict__ cat_emb,
        const float* __restrict__ w_cat, const float* __restrict__ click_emb,
        const float* __restrict__ click_w, const float* __restrict__ click_b,
        float* __restrict__ out_cat, float* __restrict__ user,
        const int* __restrict__ flagp) {
    int b = blockIdx.x, tid = threadIdx.x;
    int wave = tid >> 6, lane = tid & 63;
    int flag = *flagp;
    __shared__ float plds[HIS][20];
    __shared__ float redbuf[NUM_CAT][12];
    __shared__ float clicks[NUM_CAT];
    __shared__ int   cnts[NUM_CAT];
    __shared__ float logit[NUM_CAT];

    for (int c = wave; c < NUM_CAT; c += 12) {
        bool m = false; float v = -INFINITY;
        if (lane < HIS) {
            m = read_mask(cmask, (b * NUM_CAT + c) * HIS + lane, flag);
            if (m) v = news_w[b * HIS + lane];
        }
        unsigned long long bal = __ballot(m);
        int cnt = __popcll(bal);
        float maxv = v;
        #pragma unroll
        for (int off = 32; off; off >>= 1) maxv = fmaxf(maxv, __shfl_xor(maxv, off));
        float e = (v == -INFINITY) ? 0.f : expf(v - maxv);
        float sum = e;
        #pragma unroll
        for (int off = 32; off; off >>= 1) sum += __shfl_xor(sum, off);
        if (lane < HIS)
            plds[lane][c] = (cnt == 0 || v == -INFINITY) ? 0.f : e / sum;
        float cs = 0.f;
        if (lane < HIS) {
            const float* ce = click_emb + (size_t)cnt * CLICK_DIM;
            cs = ce[lane] * click_w[lane] + ce[lane + HIS] * click_w[lane + HIS];
        }
        #pragma unroll
        for (int off = 32; off; off >>= 1) cs += __shfl_down(cs, off);
        if (lane == 0) { cnts[c] = cnt; clicks[c] = cs + click_b[0]; }
    }
    __syncthreads();

    int col = tid;
    const unsigned short* nrb = nr + (size_t)b * HIS * EMBED;
    float acc[NUM_CAT];
    #pragma unroll
    for (int c = 0; c < NUM_CAT; ++c) acc[c] = 0.f;
    #pragma unroll 5
    for (int h = 0; h < HIS; ++h) {
        float v = bf2f(nrb[h * EMBED + col]);
        #pragma unroll
        for (int c = 0; c < NUM_CAT; ++c) acc[c] += plds[h][c] * v;
    }
    float part[NUM_CAT];
    float wv = w_cat[col];
    float* ocb = out_cat + (size_t)b * NUM_CAT * EMBED;
    #pragma unroll
    for (int c = 0; c < NUM_CAT; ++c) {
        float o = acc[c] + cat_emb[c * EMBED + col];
        acc[c] = o;
        ocb[c * EMBED + col] = o;
        part[c] = o * wv;
    }
    #pragma unroll
    for (int c = 0; c < NUM_CAT; ++c) {
        float s = part[c];
        #pragma unroll
        for (int off = 32; off; off >>= 1) s += __shfl_down(s, off);
        if (lane == 0) redbuf[c][wave] = s;
    }
    __syncthreads();
    if (tid < NUM_CAT) {
        float s = 0.f;
        #pragma unroll
        for (int w = 0; w < 12; ++w) s += redbuf[tid][w];
        logit[tid] = (cnts[tid] == 0) ? -INFINITY : (s + clicks[tid]);
    }
    __syncthreads();

    float maxv = -INFINITY;
    #pragma unroll
    for (int c = 0; c < NUM_CAT; ++c) maxv = fmaxf(maxv, logit[c]);
    float sum = 0.f;
    #pragma unroll
    for (int c = 0; c < NUM_CAT; ++c)
        sum += (logit[c] == -INFINITY) ? 0.f : expf(logit[c] - maxv);
    float u = 0.f;
    #pragma unroll
    for (int c = 0; c < NUM_CAT; ++c) {
        float w = (logit[c] == -INFINITY) ? 0.f : expf(logit[c] - maxv) / sum;
        u += w * acc[c];
    }
    user[(size_t)b * EMBED + col] = u;
}

extern "C" void kernel_launch(void* const* d_in, const int* in_sizes, int n_in,
                              void* d_out, int out_size, void* d_ws, size_t ws_size,
                              hipStream_t stream) {
    const int*   enc    = (const int*)d_in[0];
    const void*  amask  = d_in[1];
    const void*  cmask  = d_in[2];
    const float* wemb   = (const float*)d_in[3];
    const float* projw  = (const float*)d_in[4];
    const float* projb  = (const float*)d_in[5];
    const float* catemb = (const float*)d_in[6];
    const float* wna    = (const float*)d_in[7];
    const float* wca    = (const float*)d_in[8];
    const float* clemb  = (const float*)d_in[9];
    const float* clw    = (const float*)d_in[10];
    const float* clb    = (const float*)d_in[11];

    unsigned char* wsb = (unsigned char*)d_ws;
    __hip_bfloat16* pooled = (__hip_bfloat16*)(wsb + OFF_POOLED);
    __hip_bfloat16* Wt     = (__hip_bfloat16*)(wsb + OFF_WT);
    unsigned short* nr     = (unsigned short*)(wsb + OFF_NR);
    float* news_w = (float*)(wsb + OFF_NEWSW);
    int*   flag   = (int*)(wsb + OFF_FLAG);
    signed char* qtab = (signed char*)(wsb + OFF_QTAB);
    float* dscales = (float*)(wsb + OFF_DSCALE);

    float* out_cat = (float*)d_out;
    float* user    = (float*)d_out + BATCH * NUM_CAT * EMBED;

    if (ws_size >= WS_NEED) {
        kprep<<<577 + VOCAB, 256, 0, stream>>>(
            projw, Wt, (const unsigned int*)cmask, flag, wemb, qtab, dscales, news_w);
        k1c_pool<<<1600, 192, 0, stream>>>(enc, amask, (const unsigned char*)qtab,
                                           dscales, pooled, flag);
    } else {
        k0_detect<<<1, 1024, 0, stream>>>((const unsigned int*)cmask, flag, news_w);
        dim3 gt(24, 24);
        k2a_wt<<<gt, 256, 0, stream>>>(projw, Wt);
        k1_pool<<<3200, 192, 0, stream>>>(enc, amask, wemb, pooled, flag);
    }
    dim3 g2(50, 12);
    k2_mfma<<<g2, 256, 0, stream>>>(pooled, Wt, projb, wna, nr, news_w);
    k4_fused<<<BATCH, 768, 0, stream>>>(cmask, nr, news_w, catemb, wca,
                                        clemb, clw, clb, out_cat, user, flag);
}